// Round 6
// baseline (342.029 us; speedup 1.0000x reference)
//
#include <hip/hip_runtime.h>
#include <hip/hip_fp16.h>
#include <math.h>

#define NE 16
#define HD 1024
#define FD 2048
#define TWO_F 4096

typedef _Float16 half8 __attribute__((ext_vector_type(8)));
typedef float f32x4 __attribute__((ext_vector_type(4)));

// ws layout (4-byte units)
#define TOPI_OFF 0          // 256 int
#define TOPW_OFF 256        // 256 float
#define CNT_OFF  512        // 16 int
#define PREF_OFF 528        // 16 int
#define SLOT_OFF 544        // 256 int (pair -> slot)
#define INVT_OFF 800        // 256 int (slot -> token)
#define XG_OFF   4096       // 256*1024 fp16 = 131072 ints
#define HBUF_OFF (XG_OFF + 131072)    // 256*2048 fp16 = 262144 ints
#define YBUF_OFF (HBUF_OFF + 262144)  // 256*1024 f32

// fp4 e2m1 nibble -> fp16 bits (unscaled)
__device__ __forceinline__ int fp4h(int nib) {
    int c = nib & 7;
    int v;
    if (c == 0) v = 0;
    else if (c == 1) v = 14 << 10;                        // 0.5
    else v = (((c >> 1) + 14) << 10) | ((c & 1) << 9);    // 2^(e-1)*(1+m/2)
    v |= (nib & 8) << 12;                                 // sign
    return v;
}

// LUT byte -> 2 packed fp16, multiplied by packed power-of-2 scale (exact)
__device__ __forceinline__ int declut(const int* lut, int raw, int scl2) {
    int l = lut[raw & 255];
    __half2 p = *reinterpret_cast<const __half2*>(&l);
    __half2 sc = *reinterpret_cast<const __half2*>(&scl2);
    __half2 r = __hmul2(p, sc);
    return *reinterpret_cast<int*>(&r);
}

__global__ void routing_kernel(const float* __restrict__ x, const float* __restrict__ rw,
                               int* __restrict__ top_idx, float* __restrict__ top_w) {
    int t = blockIdx.x;
    int tid = threadIdx.x;          // 256
    int e = tid >> 4, seg = tid & 15;
    const float* xr = x + t * HD + seg * 64;
    const float* wr = rw + e * HD + seg * 64;
    float p = 0.f;
    #pragma unroll 8
    for (int i = 0; i < 64; ++i) p += xr[i] * wr[i];
    __shared__ float part[16][16];
    __shared__ float logit[16];
    part[e][seg] = p;
    __syncthreads();
    if (tid < 16) {
        float s = 0.f;
        #pragma unroll
        for (int i = 0; i < 16; ++i) s += part[tid][i];
        logit[tid] = s;
    }
    __syncthreads();
    if (tid == 0) {
        int i0 = 0; float v0 = logit[0];
        #pragma unroll
        for (int i = 1; i < 16; ++i) { if (logit[i] > v0) { v0 = logit[i]; i0 = i; } }
        int i1 = -1; float v1 = -1e30f;
        #pragma unroll
        for (int i = 0; i < 16; ++i) { if (i != i0 && logit[i] > v1) { v1 = logit[i]; i1 = i; } }
        float w0 = 1.f / (1.f + expf(v1 - v0));
        float w1 = 1.f / (1.f + expf(v0 - v1));
        top_idx[t * 2]     = i0;  top_w[t * 2]     = w0;
        top_idx[t * 2 + 1] = i1;  top_w[t * 2 + 1] = w1;
    }
}

// 256 threads, one per (token, k) pair. Slot order within an expert is arbitrary
// (atomics) but per-pair computation is order-independent -> output deterministic.
__global__ void build_kernel(const int* __restrict__ top_idx,
                             int* __restrict__ cnt, int* __restrict__ pref,
                             int* __restrict__ slot, int* __restrict__ invtok) {
    __shared__ int scnt[16], spref[16], scur[16];
    int tid = threadIdx.x;
    if (tid < 16) scnt[tid] = 0;
    __syncthreads();
    int e = top_idx[tid];
    atomicAdd(&scnt[e], 1);
    __syncthreads();
    if (tid == 0) {
        int s = 0;
        for (int i = 0; i < 16; ++i) { spref[i] = s; pref[i] = s; cnt[i] = scnt[i]; s += scnt[i]; }
    }
    if (tid < 16) scur[tid] = 0;
    __syncthreads();
    int pos = spref[e] + atomicAdd(&scur[e], 1);
    slot[tid] = pos;
    invtok[pos] = tid >> 1;
}

__global__ void gather_kernel(const float* __restrict__ x, const int* __restrict__ invtok,
                              _Float16* __restrict__ xg) {
    int slt = blockIdx.x;           // 256
    int t = invtok[slt];
    int i = threadIdx.x;            // 256 threads x 4 elems
    float4 v = ((const float4*)(x + (long)t * HD))[i];
    union { _Float16 h[4]; int2 p; } o;
    o.h[0] = (_Float16)v.x; o.h[1] = (_Float16)v.y;
    o.h[2] = (_Float16)v.z; o.h[3] = (_Float16)v.w;
    ((int2*)(xg + (long)slt * HD))[i] = o.p;
}

// gu GEMM + SwiGLU via 16x16x32 f16 MFMA, K SPLIT ACROSS THE 4 WAVES (8 steps each),
// LDS cross-wave reduction, single epilogue (one output element per thread).
__global__ __launch_bounds__(256, 4) void gemm1_mfma(
    const _Float16* __restrict__ xg, const int* __restrict__ qblk,
    const int* __restrict__ qscl, const float* __restrict__ bias,
    const int* __restrict__ cnt, const int* __restrict__ pref,
    _Float16* __restrict__ hbuf) {
    int e  = blockIdx.x >> 10;          // 128 ft x 8 mt per expert
    int ft = (blockIdx.x >> 3) & 127;   // 16 f-cols (gate row-tile ft, up row-tile ft+FD)
    int mt = blockIdx.x & 7;
    int n = cnt[e];
    if (mt * 16 >= n) return;
    __shared__ int lut[256];
    __shared__ float sred[4][2][64][4];
    int tid = threadIdx.x;
    lut[tid] = fp4h(tid & 15) | (fp4h(tid >> 4) << 16);
    __syncthreads();
    int wave = tid >> 6, lane = tid & 63;
    int col = lane & 15;
    int kb = lane >> 4;
    long rg = (long)e * TWO_F + ft * 16 + col;    // gate row
    long ru = rg + FD;                            // up row
    const int4* bg_p = (const int4*)(qblk + rg * 512);
    const int4* bu_p = (const int4*)(qblk + ru * 512);
    union { int4 v[2]; int s[8]; } sgu, suu;
    { const int4* p = (const int4*)(qscl + rg * 32); sgu.v[0] = p[wave*2]; sgu.v[1] = p[wave*2+1]; }
    { const int4* p = (const int4*)(qscl + ru * 32); suu.v[0] = p[wave*2]; suu.v[1] = p[wave*2+1]; }
    int base = pref[e];
    int arow = base + mt * 16 + col;              // ragged rows: computed, never stored
    if (arow > 255) arow = 255;
    const _Float16* ax = xg + (long)arow * HD + kb * 8;

    f32x4 accg = {0.f, 0.f, 0.f, 0.f}, accu = {0.f, 0.f, 0.f, 0.f};
    #pragma unroll
    for (int i = 0; i < 8; ++i) {
        int s = wave * 8 + i;                     // this wave's K chunk
        half8 a = *(const half8*)(ax + 32 * s);
        int4 bgq = bg_p[kb + 4 * s];
        int4 buq = bu_p[kb + 4 * s];
        int g2 = (sgu.s[i] - 112) << 10; g2 |= g2 << 16;   // 2^(s-127) as packed fp16
        int u2 = (suu.s[i] - 112) << 10; u2 |= u2 << 16;
        union { int i4[4]; half8 h; } dg, du;
        dg.i4[0] = declut(lut, bgq.x, g2); dg.i4[1] = declut(lut, bgq.y, g2);
        dg.i4[2] = declut(lut, bgq.z, g2); dg.i4[3] = declut(lut, bgq.w, g2);
        du.i4[0] = declut(lut, buq.x, u2); du.i4[1] = declut(lut, buq.y, u2);
        du.i4[2] = declut(lut, buq.z, u2); du.i4[3] = declut(lut, buq.w, u2);
        accg = __builtin_amdgcn_mfma_f32_16x16x32_f16(a, dg.h, accg, 0, 0, 0);
        accu = __builtin_amdgcn_mfma_f32_16x16x32_f16(a, du.h, accu, 0, 0, 0);
    }
    #pragma unroll
    for (int r = 0; r < 4; ++r) {
        sred[wave][0][lane][r] = accg[r];
        sred[wave][1][lane][r] = accu[r];
    }
    __syncthreads();
    // epilogue: thread tid -> element (lane=tid&63, reg=tid>>6) of the 16x16 D tile
    int l2 = tid & 63, r2 = tid >> 6;
    float gg = sred[0][0][l2][r2] + sred[1][0][l2][r2] + sred[2][0][l2][r2] + sred[3][0][l2][r2];
    float uu = sred[0][1][l2][r2] + sred[1][1][l2][r2] + sred[2][1][l2][r2] + sred[3][1][l2][r2];
    int row = mt * 16 + ((l2 >> 4) << 2) + r2;    // D: col=lane&15, row=(lane>>4)*4+reg
    if (row < n) {
        int f = ft * 16 + (l2 & 15);
        float g = gg + bias[(long)e * TWO_F + f];
        float u = uu + bias[(long)e * TWO_F + FD + f];
        float h = (g / (1.f + expf(-g))) * u;
        hbuf[(long)(base + row) * FD + f] = (_Float16)(h * 0.0625f);  // 2^-4, exact shift
    }
}

// down GEMM via MFMA, K=2048 split across 4 waves (16 steps each), LDS reduce.
__global__ __launch_bounds__(256, 4) void gemm2_mfma(
    const _Float16* __restrict__ hbuf, const int* __restrict__ qblk,
    const int* __restrict__ qscl, const float* __restrict__ bias,
    const int* __restrict__ cnt, const int* __restrict__ pref,
    float* __restrict__ ybuf) {
    int e  = blockIdx.x >> 9;           // 64 ht x 8 mt per expert
    int ht = (blockIdx.x >> 3) & 63;
    int mt = blockIdx.x & 7;
    int n = cnt[e];
    if (mt * 16 >= n) return;
    __shared__ int lut[256];
    __shared__ float sred[4][64][4];
    int tid = threadIdx.x;
    lut[tid] = fp4h(tid & 15) | (fp4h(tid >> 4) << 16);
    __syncthreads();
    int wave = tid >> 6, lane = tid & 63;
    int col = lane & 15;
    int kb = lane >> 4;
    long r = (long)e * HD + ht * 16 + col;
    const int4* b_p = (const int4*)(qblk + r * 1024);
    union { int4 v[4]; int s[16]; } scl;
    { const int4* p = (const int4*)(qscl + r * 64);
      scl.v[0] = p[wave*4]; scl.v[1] = p[wave*4+1]; scl.v[2] = p[wave*4+2]; scl.v[3] = p[wave*4+3]; }
    int base = pref[e];
    int arow = base + mt * 16 + col;
    if (arow > 255) arow = 255;
    const _Float16* ax = hbuf + (long)arow * FD + kb * 8;

    f32x4 acc = {0.f, 0.f, 0.f, 0.f};
    #pragma unroll
    for (int i = 0; i < 16; ++i) {
        int s = wave * 16 + i;
        half8 a = *(const half8*)(ax + 32 * s);
        int4 bq = b_p[kb + 4 * s];
        int c2 = (scl.s[i] - 112) << 10; c2 |= c2 << 16;
        union { int i4[4]; half8 h; } w;
        w.i4[0] = declut(lut, bq.x, c2); w.i4[1] = declut(lut, bq.y, c2);
        w.i4[2] = declut(lut, bq.z, c2); w.i4[3] = declut(lut, bq.w, c2);
        acc = __builtin_amdgcn_mfma_f32_16x16x32_f16(a, w.h, acc, 0, 0, 0);
    }
    #pragma unroll
    for (int rr = 0; rr < 4; ++rr) sred[wave][lane][rr] = acc[rr];
    __syncthreads();
    int l2 = tid & 63, r2 = tid >> 6;
    float aa = sred[0][l2][r2] + sred[1][l2][r2] + sred[2][l2][r2] + sred[3][l2][r2];
    int row = mt * 16 + ((l2 >> 4) << 2) + r2;
    if (row < n) {
        int hcol = ht * 16 + (l2 & 15);
        ybuf[(long)(base + row) * HD + hcol] = aa * 16.f + bias[(long)e * HD + hcol];
    }
}

__global__ void combine_kernel(const float* __restrict__ ybuf, const int* __restrict__ slot,
                               const float* __restrict__ topw, float* __restrict__ out) {
    int t = blockIdx.x;
    int i = threadIdx.x;   // 256, float4 each
    int s0 = slot[2 * t], s1 = slot[2 * t + 1];
    float w0 = topw[2 * t], w1 = topw[2 * t + 1];
    float4 a = ((const float4*)(ybuf + (long)s0 * HD))[i];
    float4 b = ((const float4*)(ybuf + (long)s1 * HD))[i];
    float4 o;
    o.x = w0 * a.x + w1 * b.x;
    o.y = w0 * a.y + w1 * b.y;
    o.z = w0 * a.z + w1 * b.z;
    o.w = w0 * a.w + w1 * b.w;
    ((float4*)(out + (long)t * HD))[i] = o;
}

extern "C" void kernel_launch(void* const* d_in, const int* in_sizes, int n_in,
                              void* d_out, int out_size, void* d_ws, size_t ws_size,
                              hipStream_t stream) {
    const float* x          = (const float*)d_in[0];
    const float* rw         = (const float*)d_in[1];
    const float* bias_gu    = (const float*)d_in[2];
    const float* bias_down  = (const float*)d_in[3];
    const int*   blocks_gu  = (const int*)d_in[4];
    const int*   scales_gu  = (const int*)d_in[5];
    const int*   blocks_down= (const int*)d_in[6];
    const int*   scales_down= (const int*)d_in[7];
    float* out = (float*)d_out;
    int*   wsI = (int*)d_ws;
    float* wsF = (float*)d_ws;
    _Float16* xg   = (_Float16*)(wsI + XG_OFF);
    _Float16* hbuf = (_Float16*)(wsI + HBUF_OFF);
    float*    ybuf = wsF + YBUF_OFF;

    routing_kernel<<<128, 256, 0, stream>>>(x, rw, wsI + TOPI_OFF, wsF + TOPW_OFF);
    build_kernel<<<1, 256, 0, stream>>>(wsI + TOPI_OFF, wsI + CNT_OFF, wsI + PREF_OFF,
                                        wsI + SLOT_OFF, wsI + INVT_OFF);
    gather_kernel<<<256, 256, 0, stream>>>(x, wsI + INVT_OFF, xg);
    gemm1_mfma<<<NE * 128 * 8, 256, 0, stream>>>(xg, blocks_gu, scales_gu, bias_gu,
                                                 wsI + CNT_OFF, wsI + PREF_OFF, hbuf);
    gemm2_mfma<<<NE * 64 * 8, 256, 0, stream>>>(hbuf, blocks_down, scales_down, bias_down,
                                                wsI + CNT_OFF, wsI + PREF_OFF, ybuf);
    combine_kernel<<<128, 256, 0, stream>>>(ybuf, wsI + SLOT_OFF, wsF + TOPW_OFF, out);
}